// Round 11
// baseline (96.038 us; speedup 1.0000x reference)
//
#include <hip/hip_runtime.h>
#include <stdint.h>

typedef __bf16 bf16x8 __attribute__((ext_vector_type(8)));
typedef float f32x4 __attribute__((ext_vector_type(4)));
typedef __attribute__((address_space(3))) uint32_t as3u32;
typedef const __attribute__((address_space(1))) uint32_t as1u32;

#define B_TOT 8192
#define DD 128
#define OUT_TOT 67108864UL
#define OUT_AVG 67117056UL

__device__ inline unsigned short f2bf(float x){
  union { float f; uint32_t u; } v; v.f = x;
  return (unsigned short)((v.u + 0x7fffu + ((v.u >> 16) & 1u)) >> 16);
}

// ------- phase 1: gather + normalize + h + pos; one wave per sample ------------
__global__ __launch_bounds__(256) void k_feat(const float* __restrict__ x1,
    const float* __restrict__ x2, const int* __restrict__ i1a, const int* __restrict__ i2a,
    unsigned short* __restrict__ f1b, unsigned short* __restrict__ f2b,
    unsigned short* __restrict__ hb, float* __restrict__ posw, float* __restrict__ out){
  int tid = threadIdx.x;
  int gid = blockIdx.x * 256 + tid;
  if (gid <= 8192) out[OUT_TOT + gid] = 0.f;   // zero tot accum + avg slot
  int w = tid >> 6, l = tid & 63;
  int b = blockIdx.x * 4 + w;                  // grid 2048 -> b 0..8191
  const float2* r1 = (const float2*)(x1 + (size_t)i1a[b] * DD);
  const float2* r2 = (const float2*)(x2 + (size_t)i2a[b] * DD);
  float2 v1 = r1[l], v2 = r2[l];
  float s1 = v1.x * v1.x + v1.y * v1.y;
  float s2 = v2.x * v2.x + v2.y * v2.y;
  #pragma unroll
  for (int o = 32; o; o >>= 1){ s1 += __shfl_xor(s1, o); s2 += __shfl_xor(s2, o); }
  float inv1 = 1.f / fmaxf(sqrtf(s1), 1e-12f);
  float inv2 = 1.f / fmaxf(sqrtf(s2), 1e-12f);
  float f1x = v1.x * inv1, f1y = v1.y * inv1;
  float f2x = v2.x * inv2, f2y = v2.y * inv2;
  float hx = f1x * f2x, hy = f1y * f2y;
  float ps = hx + hy;
  #pragma unroll
  for (int o = 32; o; o >>= 1) ps += __shfl_xor(ps, o);
  unsigned int u1 = (unsigned int)f2bf(f1x) | ((unsigned int)f2bf(f1y) << 16);
  unsigned int u2 = (unsigned int)f2bf(f2x) | ((unsigned int)f2bf(f2y) << 16);
  unsigned int uh = (unsigned int)f2bf(hx)  | ((unsigned int)f2bf(hy)  << 16);
  ((unsigned int*)f1b)[b * 64 + l] = u1;
  ((unsigned int*)f2b)[b * 64 + l] = u2;
  ((unsigned int*)hb)[b * 64 + l]  = uh;
  if (l == 0) posw[b] = ps;
}

// ---------------- shared staging (128x128 bf16 tile, XOR-swizzled) ----------------
__device__ inline void stage_tile(const unsigned short* g, unsigned short* s){
  int tid = threadIdx.x;
  #pragma unroll
  for (int it = 0; it < 8; ++it){
    int c = tid + it * 256;          // 2048 chunks of 16B
    int row = c >> 4, cc = c & 15;
    int src = (row << 4) + (cc ^ (row & 7));
    __builtin_amdgcn_global_load_lds((as1u32*)(g + src * 8),
                                     (as3u32*)(s + c * 8), 16, 0, 0);
  }
}

// A-frag: row = lane&15, k = 8*(lane>>4)+e. C/D: col = lane&15, row=(lane>>4)*4+reg.
__device__ inline void mfma_tile(const unsigned short* As, const unsigned short* Bs,
                                 f32x4 acc[4][4]){
  int tid = threadIdx.x;
  int w = tid >> 6, l = tid & 63;
  int wr = (w >> 1) * 64, wc = (w & 1) * 64;
  int lo = l & 15, hi = l >> 4;
  f32x4 zero = {0.f, 0.f, 0.f, 0.f};
  #pragma unroll
  for (int m = 0; m < 4; ++m)
    #pragma unroll
    for (int n = 0; n < 4; ++n) acc[m][n] = zero;
  #pragma unroll
  for (int kk = 0; kk < 4; ++kk){
    bf16x8 af[4], bfv[4];
    #pragma unroll
    for (int m = 0; m < 4; ++m){
      int row = wr + m * 16 + lo;
      af[m] = *(const bf16x8*)(As + row * 128 + ((kk * 4 + hi) ^ (row & 7)) * 8);
    }
    #pragma unroll
    for (int n = 0; n < 4; ++n){
      int row = wc + n * 16 + lo;
      bfv[n] = *(const bf16x8*)(Bs + row * 128 + ((kk * 4 + hi) ^ (row & 7)) * 8);
    }
    #pragma unroll
    for (int m = 0; m < 4; ++m)
      #pragma unroll
      for (int n = 0; n < 4; ++n)
        acc[m][n] = __builtin_amdgcn_mfma_f32_16x16x32_bf16(af[m], bfv[n], acc[m][n], 0, 0, 0);
  }
}

// ---------------- phase 2: lin1 + leaky + lin2 + sigmoid -> rT, temp-mean -------
__global__ __launch_bounds__(256) void k_lin(const unsigned short* __restrict__ hb,
    const float* __restrict__ W1, const float* __restrict__ b1,
    const float* __restrict__ W2, const float* __restrict__ b2,
    float* __restrict__ rTw, float* __restrict__ out){
  __shared__ __align__(16) unsigned short As[16384];
  __shared__ __align__(16) unsigned short Bs[16384];
  __shared__ float zpart[2][128];
  __shared__ float s4[4];
  int i0 = blockIdx.x * 128;
  int tid = threadIdx.x;
  stage_tile(hb + (size_t)i0 * 128, As);
  #pragma unroll
  for (int it = 0; it < 8; ++it){
    int c = tid + it * 256;
    int row = c >> 4, cc = c & 15;
    int src = (row << 4) + (cc ^ (row & 7));
    const float4* g4 = (const float4*)(W1 + src * 8);
    float4 a = g4[0], b = g4[1];
    unsigned short t8[8];
    t8[0] = f2bf(a.x); t8[1] = f2bf(a.y); t8[2] = f2bf(a.z); t8[3] = f2bf(a.w);
    t8[4] = f2bf(b.x); t8[5] = f2bf(b.y); t8[6] = f2bf(b.z); t8[7] = f2bf(b.w);
    *(uint4*)(Bs + c * 8) = *(uint4*)t8;
  }
  asm volatile("s_waitcnt vmcnt(0)" ::: "memory");
  __syncthreads();
  f32x4 acc[4][4];
  mfma_tile(As, Bs, acc);
  int w = tid >> 6, l = tid & 63;
  int wrb = (w >> 1) * 64, wcb = (w & 1) * 64, lo = l & 15, hi = l >> 4;
  float w2v[4], b1v[4];
  #pragma unroll
  for (int n = 0; n < 4; ++n){ int col = wcb + n * 16 + lo; w2v[n] = W2[col]; b1v[n] = b1[col]; }
  #pragma unroll
  for (int m = 0; m < 4; ++m){
    #pragma unroll
    for (int q = 0; q < 4; ++q){
      float p = 0.f;
      #pragma unroll
      for (int n = 0; n < 4; ++n){
        float hv = acc[m][n][q] + b1v[n];
        hv = hv >= 0.f ? hv : 0.2f * hv;   // leaky_relu(0.2)
        p += hv * w2v[n];
      }
      p += __shfl_xor(p, 1); p += __shfl_xor(p, 2);
      p += __shfl_xor(p, 4); p += __shfl_xor(p, 8);
      if (lo == 0) zpart[w & 1][wrb + m * 16 + hi * 4 + q] = p;
    }
  }
  __syncthreads();
  float Tloc = 0.f;
  if (tid < 128){
    float z = zpart[0][tid] + zpart[1][tid] + b2[0];
    float s = 1.f / (1.f + __expf(-z));
    float T = 0.95f * (1.f - s) + 0.05f;
    rTw[i0 + tid] = 1.f / T;
    Tloc = T;
  }
  float v = Tloc;
  #pragma unroll
  for (int o = 32; o; o >>= 1) v += __shfl_xor(v, o);
  if ((tid & 63) == 0) s4[tid >> 6] = v;
  __syncthreads();
  if (tid == 0) atomicAdd(out + OUT_AVG, (s4[0] + s4[1] + s4[2] + s4[3]) * (1.0f / 8192.0f));
}

// ------- phase 3: tot GEMM only (A in regs, B looped through LDS) ---------------
__global__ __launch_bounds__(256, 2) void k_tot(const unsigned short* __restrict__ f1b,
    const unsigned short* __restrict__ f2b, const float* __restrict__ rTw,
    float* __restrict__ out){
  __shared__ __align__(16) unsigned short Buf[16384];   // 32 KB
  __shared__ __align__(16) float rS[128];
  int s = (blockIdx.x & 7) * 64 + (blockIdx.x >> 3);    // XCD-chunked, bijective
  int rt = s & 63, ctg = s >> 6;
  int tid = threadIdx.x, w = tid >> 6, l = tid & 63;
  int wr = (w >> 1) * 64, wc = (w & 1) * 64;
  int lo = l & 15, hi = l >> 4;
  stage_tile(f1b + (size_t)rt * 16384, Buf);
  if (tid < 32)
    __builtin_amdgcn_global_load_lds((as1u32*)(rTw + rt * 128 + tid * 4),
                                     (as3u32*)(rS + tid * 4), 16, 0, 0);
  asm volatile("s_waitcnt vmcnt(0)" ::: "memory");
  __builtin_amdgcn_s_barrier();
  bf16x8 af[4][4];                 // A fragments in registers
  #pragma unroll
  for (int kk = 0; kk < 4; ++kk)
    #pragma unroll
    for (int m = 0; m < 4; ++m){
      int row = wr + m * 16 + lo;
      af[kk][m] = *(const bf16x8*)(Buf + row * 128 + ((kk * 4 + hi) ^ (row & 7)) * 8);
    }
  asm volatile("s_waitcnt lgkmcnt(0)" ::: "memory");
  __builtin_amdgcn_s_barrier();    // Buf free for B staging
  stage_tile(f2b + (size_t)(ctg * 8) * 16384, Buf);
  asm volatile("s_waitcnt vmcnt(0)" ::: "memory");
  __builtin_amdgcn_s_barrier();    // B(0) ready
  float pacc[4][4] = {{0.f,0.f,0.f,0.f},{0.f,0.f,0.f,0.f},{0.f,0.f,0.f,0.f},{0.f,0.f,0.f,0.f}};
  #pragma unroll 1
  for (int c8 = 0; c8 < 8; ++c8){
    int ct = ctg * 8 + c8;
    f32x4 acc[4][4];
    f32x4 zero = {0.f,0.f,0.f,0.f};
    #pragma unroll
    for (int m = 0; m < 4; ++m)
      #pragma unroll
      for (int n = 0; n < 4; ++n) acc[m][n] = zero;
    #pragma unroll
    for (int kk = 0; kk < 4; ++kk){
      bf16x8 bfv[4];
      #pragma unroll
      for (int n = 0; n < 4; ++n){
        int row = wc + n * 16 + lo;
        bfv[n] = *(const bf16x8*)(Buf + row * 128 + ((kk * 4 + hi) ^ (row & 7)) * 8);
      }
      #pragma unroll
      for (int m = 0; m < 4; ++m)
        #pragma unroll
        for (int n = 0; n < 4; ++n)
          acc[m][n] = __builtin_amdgcn_mfma_f32_16x16x32_bf16(af[kk][m], bfv[n], acc[m][n], 0, 0, 0);
    }
    asm volatile("s_waitcnt lgkmcnt(0)" ::: "memory");
    __builtin_amdgcn_s_barrier();        // all waves done reading Buf
    if (c8 < 7) stage_tile(f2b + (size_t)(ct + 1) * 16384, Buf);   // prefetch next
    // exp accumulation overlaps the in-flight loads
    #pragma unroll
    for (int m = 0; m < 4; ++m)
      #pragma unroll
      for (int q = 0; q < 4; ++q){
        float r = rS[wr + m * 16 + hi * 4 + q];
        pacc[m][q] += __expf(acc[m][0][q] * r) + __expf(acc[m][1][q] * r)
                    + __expf(acc[m][2][q] * r) + __expf(acc[m][3][q] * r);
      }
    if (c8 < 7){
      asm volatile("s_waitcnt vmcnt(0)" ::: "memory");
      __builtin_amdgcn_s_barrier();      // B(c8+1) ready
    }
  }
  // tot partials: reduce across the 16 col-lanes, one atomic set per block
  #pragma unroll
  for (int m = 0; m < 4; ++m)
    #pragma unroll
    for (int q = 0; q < 4; ++q){
      float p = pacc[m][q];
      p += __shfl_xor(p, 1); p += __shfl_xor(p, 2);
      p += __shfl_xor(p, 4); p += __shfl_xor(p, 8);
      if (lo == 0) atomicAdd(out + OUT_TOT + rt * 128 + wr + m * 16 + hi * 4 + q, p);
    }
}

// ------- phase 4: pos_rating writer v3 — read-free after prologue --------------
// 512 blocks x 256 threads; block bid owns rows [16*bid, 16*bid+16) = one
// contiguous 512 KB slab. ALL inputs (8 pos vectors + 16 rT) in registers before
// the store stream starts; loops fully unrolled (static rr index, rule #20);
// nt stores keep the 268 MB stream from churning L2.
__global__ __launch_bounds__(256) void k_pr(const float* __restrict__ posw,
    const float* __restrict__ rTw, float* __restrict__ out){
  int tid = threadIdx.x;
  int r0 = blockIdx.x * 16;
  f32x4 p[8];
  #pragma unroll
  for (int c = 0; c < 8; ++c) p[c] = *(const f32x4*)(posw + (c * 256 + tid) * 4);
  float rr[16];
  #pragma unroll
  for (int q = 0; q < 4; ++q){
    float4 r4 = *(const float4*)(rTw + r0 + q * 4);
    rr[q * 4 + 0] = r4.x; rr[q * 4 + 1] = r4.y;
    rr[q * 4 + 2] = r4.z; rr[q * 4 + 3] = r4.w;
  }
  #pragma unroll
  for (int r = 0; r < 16; ++r){
    float* ob = out + (size_t)(r0 + r) * B_TOT;
    float rv = rr[r];
    #pragma unroll
    for (int c = 0; c < 8; ++c){
      f32x4 e;
      e.x = __expf(p[c].x * rv); e.y = __expf(p[c].y * rv);
      e.z = __expf(p[c].z * rv); e.w = __expf(p[c].w * rv);
      __builtin_nontemporal_store(e, (f32x4*)(ob + (c * 256 + tid) * 4));
    }
  }
}

extern "C" void kernel_launch(void* const* d_in, const int* in_sizes, int n_in,
                              void* d_out, int out_size, void* d_ws, size_t ws_size,
                              hipStream_t stream){
  const float* x1 = (const float*)d_in[0];
  const float* x2 = (const float*)d_in[1];
  const int*   i1 = (const int*)d_in[2];
  const int*   i2 = (const int*)d_in[3];
  const float* W1 = (const float*)d_in[4];
  const float* b1 = (const float*)d_in[5];
  const float* W2 = (const float*)d_in[6];
  const float* b2 = (const float*)d_in[7];
  float* out = (float*)d_out;
  char* ws = (char*)d_ws;
  unsigned short* hb   = (unsigned short*)(ws);              // 2 MB
  unsigned short* f1b  = (unsigned short*)(ws + 2097152);    // 2 MB
  unsigned short* f2b  = (unsigned short*)(ws + 4194304);    // 2 MB
  float* posw  = (float*)(ws + 6291456);                     // 32 KB
  float* rTw   = (float*)(ws + 6324224);                     // 32 KB

  hipLaunchKernelGGL(k_feat, dim3(2048), dim3(256), 0, stream, x1, x2, i1, i2, f1b, f2b, hb, posw, out);
  hipLaunchKernelGGL(k_lin,  dim3(64),   dim3(256), 0, stream, hb, W1, b1, W2, b2, rTw, out);
  hipLaunchKernelGGL(k_tot,  dim3(512),  dim3(256), 0, stream, f1b, f2b, rTw, out);
  hipLaunchKernelGGL(k_pr,   dim3(512),  dim3(256), 0, stream, posw, rTw, out);
}